// Round 7
// baseline (397.742 us; speedup 1.0000x reference)
//
#include <hip/hip_runtime.h>
#include <hip/hip_bf16.h>

#define DIM 64
#define BKN 128              // nodes per bucket
#define BKSH 7               // log2(BKN)
#define MAXBK 800            // supports N <= 102400
#define SORTB 512            // blocks for the two-pass sort
#define SORTT 512            // threads per sort block
#define CAP 7500             // stage-2 LDS record capacity (60 KB); mean is ~4096
#define NPH 4                // dim phases (16 dims each): 3.2 MB bf16 slice fits 4-MiB XCD L2

__device__ inline float fast_tanh(float x) {
    float e = __expf(2.0f * x);
    return 1.0f - 2.0f / (e + 1.0f);
}

// ---------- gates: per-node dot products + phase-split bf16 copy of h ----------
// hb layout: hb[ph][node][k] = h[node][ph*16+k], ph in [0,4), k in [0,16)
__global__ void fa_node_gates(const float* __restrict__ h,
                              const float* __restrict__ gate_W,
                              float* __restrict__ gd,
                              float* __restrict__ gs,
                              __hip_bfloat16* __restrict__ hb,   // may be null
                              int N) {
    int gid  = blockIdx.x * blockDim.x + threadIdx.x;
    int node = gid >> 6;
    int lane = threadIdx.x & 63;
    if (node >= N) return;
    float x = h[(size_t)node * DIM + lane];
    if (hb) {
        int ph = lane >> 4, k = lane & 15;
        hb[((size_t)ph * N + node) * 16 + k] = __float2bfloat16(x);
    }
    float a = x * gate_W[lane];
    float b = x * gate_W[DIM + lane];
    #pragma unroll
    for (int off = 32; off >= 1; off >>= 1) {
        a += __shfl_xor(a, off, 64);
        b += __shfl_xor(b, off, 64);
    }
    if (lane == 0) {
        gd[node] = a;
        gs[node] = b;
    }
}

// ---------- pass 1: per-block bucket histogram (cnt[blk*MAXBK + bk]) ----------
__global__ void fa_sort_hist(const int* __restrict__ edst, int* __restrict__ cnt, int E) {
    __shared__ int lh[MAXBK];
    int tid = threadIdx.x;
    for (int i = tid; i < MAXBK; i += blockDim.x) lh[i] = 0;
    __syncthreads();
    int chunk = (E + gridDim.x - 1) / gridDim.x;
    int c0 = blockIdx.x * chunk;
    int c1 = min(E, c0 + chunk);
    for (int i = c0 + tid; i < c1; i += blockDim.x)
        atomicAdd(&lh[edst[i] >> BKSH], 1);
    __syncthreads();
    for (int i = tid; i < MAXBK; i += blockDim.x)
        cnt[blockIdx.x * MAXBK + i] = lh[i];
}

// ---------- scan A: per-bucket exclusive prefix over blocks; bucket totals ----------
__global__ void fa_sort_scanA(int* __restrict__ cnt, int* __restrict__ bktot) {
    __shared__ int sc[SORTB];
    int bk  = blockIdx.x;
    int tid = threadIdx.x;
    int v = cnt[tid * MAXBK + bk];
    sc[tid] = v;
    __syncthreads();
    for (int dd = 1; dd < SORTB; dd <<= 1) {
        int t = (tid >= dd) ? sc[tid - dd] : 0;
        __syncthreads();
        sc[tid] += t;
        __syncthreads();
    }
    cnt[tid * MAXBK + bk] = sc[tid] - v;
    if (tid == SORTB - 1) bktot[bk] = sc[tid];
}

// ---------- scan B: exclusive scan of bucket totals; off[N] = E sentinel ----------
__global__ void fa_sort_scanB(const int* __restrict__ bktot, int* __restrict__ bkoff,
                              int* __restrict__ off, int nbk, int E, int N) {
    __shared__ int sc[1024];
    int tid = threadIdx.x;
    int v = (tid < nbk) ? bktot[tid] : 0;
    sc[tid] = v;
    __syncthreads();
    for (int dd = 1; dd < 1024; dd <<= 1) {
        int t = (tid >= dd) ? sc[tid - dd] : 0;
        __syncthreads();
        sc[tid] += t;
        __syncthreads();
    }
    if (tid < nbk) bkoff[tid] = sc[tid] - v;
    if (tid == 0) off[N] = E;
}

// ---------- pass 2: gate compute + place record in bucket region ----------
__global__ void fa_sort_place(const float* __restrict__ gd, const float* __restrict__ gs,
                              const float* __restrict__ d,
                              const int* __restrict__ esrc, const int* __restrict__ edst,
                              const float* __restrict__ gate_b,
                              const int* __restrict__ cnt, const int* __restrict__ bkoff,
                              int2* __restrict__ pairs, int E, int nbk) {
    __shared__ int lcur[MAXBK];
    int tid = threadIdx.x;
    for (int i = tid; i < nbk; i += blockDim.x)
        lcur[i] = bkoff[i] + cnt[blockIdx.x * MAXBK + i];
    __syncthreads();
    int chunk = (E + gridDim.x - 1) / gridDim.x;
    int c0 = blockIdx.x * chunk;
    int c1 = min(E, c0 + chunk);
    float gb = gate_b[0];
    for (int i = c0 + tid; i < c1; i += blockDim.x) {
        int t = edst[i];
        int s = esrc[i];
        float g  = fast_tanh(gd[t] + gs[s] + gb);
        float ev = g * d[t] * d[s];
        int bk = t >> BKSH;
        int pos = atomicAdd(&lcur[bk], 1);       // LDS atomic
        pairs[pos] = make_int2((s << BKSH) | (t & (BKN - 1)), __float_as_int(ev));
    }
}

// ---------- stage 2: in-LDS per-node counting sort within each bucket ----------
__global__ void fa_stage2(int2* __restrict__ pairs,
                          const int* __restrict__ bkoff, const int* __restrict__ bktot,
                          int* __restrict__ off, int* __restrict__ flags, int N) {
    __shared__ int2 buf[CAP];                    // 60 KB
    __shared__ int hist[BKN];
    __shared__ int sc[BKN];
    __shared__ int cur[BKN];
    int bk  = blockIdx.x;
    int tid = threadIdx.x;                       // 256 threads
    int s0  = bkoff[bk];
    int c   = bktot[bk];
    if (c > CAP) {                               // adversarial skew: leave unsorted
        if (tid == 0) {
            flags[bk] = 1;
            int n0 = bk << BKSH;
            if (n0 < N) off[n0] = s0;
        }
        return;
    }
    if (tid < BKN) hist[tid] = 0;
    __syncthreads();
    for (int i = tid; i < c; i += blockDim.x) {
        int2 r = pairs[s0 + i];
        buf[i] = r;
        atomicAdd(&hist[r.x & (BKN - 1)], 1);
    }
    __syncthreads();
    int v = (tid < BKN) ? hist[tid] : 0;
    if (tid < BKN) sc[tid] = v;
    __syncthreads();
    for (int dd = 1; dd < BKN; dd <<= 1) {
        int t = (tid < BKN && tid >= dd) ? sc[tid - dd] : 0;
        __syncthreads();
        if (tid < BKN) sc[tid] += t;
        __syncthreads();
    }
    if (tid < BKN) {
        int excl = sc[tid] - v;
        cur[tid] = excl;
        int node = (bk << BKSH) + tid;
        if (node < N) off[node] = s0 + excl;
    }
    __syncthreads();
    for (int i = tid; i < c; i += blockDim.x) {
        int2 r = buf[i];
        int p = atomicAdd(&cur[r.x & (BKN - 1)], 1);   // LDS atomic
        pairs[s0 + p] = r;
    }
}

// ---------- gather: wave per node x 4 dim-phases; 4 edge-groups x 16 dims ----------
__global__ void fa_gather4(const __hip_bfloat16* __restrict__ hb,
                           const int* __restrict__ off,
                           const int* __restrict__ bkoff, const int* __restrict__ bktot,
                           const int* __restrict__ flags,
                           const int2* __restrict__ pairs,
                           float* __restrict__ z, int N) {
    int gid  = blockIdx.x * blockDim.x + threadIdx.x;
    int node = gid >> 6;
    int lane = threadIdx.x & 63;
    if (node >= N) return;
    int ph = blockIdx.y;            // dim phase
    int g  = lane >> 4;             // edge group 0..3
    int k  = lane & 15;             // dim within phase
    const __hip_bfloat16* hp = hb + (size_t)ph * N * 16;
    int bk = node >> BKSH;
    float acc = 0.f;
    if (!flags[bk]) {
        int j   = off[node] + g;
        int end = off[node + 1];
        // 4-deep unrolled: this group's edges j, j+4, j+8, j+12
        for (; j + 12 < end; j += 16) {
            long long r0 = __builtin_nontemporal_load((const long long*)(pairs + j));
            long long r1 = __builtin_nontemporal_load((const long long*)(pairs + j + 4));
            long long r2 = __builtin_nontemporal_load((const long long*)(pairs + j + 8));
            long long r3 = __builtin_nontemporal_load((const long long*)(pairs + j + 12));
            int s0 = ((int)r0) >> BKSH, s1 = ((int)r1) >> BKSH;
            int s2 = ((int)r2) >> BKSH, s3 = ((int)r3) >> BKSH;
            float h0 = __bfloat162float(hp[(size_t)s0 * 16 + k]);
            float h1 = __bfloat162float(hp[(size_t)s1 * 16 + k]);
            float h2 = __bfloat162float(hp[(size_t)s2 * 16 + k]);
            float h3 = __bfloat162float(hp[(size_t)s3 * 16 + k]);
            acc += h0 * __int_as_float((int)(r0 >> 32));
            acc += h1 * __int_as_float((int)(r1 >> 32));
            acc += h2 * __int_as_float((int)(r2 >> 32));
            acc += h3 * __int_as_float((int)(r3 >> 32));
        }
        for (; j < end; j += 4) {
            long long r = __builtin_nontemporal_load((const long long*)(pairs + j));
            int s = ((int)r) >> BKSH;
            acc += __bfloat162float(hp[(size_t)s * 16 + k]) * __int_as_float((int)(r >> 32));
        }
    } else {
        // correct slow path for oversized (unsorted) buckets
        int s0 = bkoff[bk], end = s0 + bktot[bk];
        int want = node & (BKN - 1);
        for (int j = s0 + g; j < end; j += 4) {
            int2 p = pairs[j];
            if ((p.x & (BKN - 1)) == want)
                acc += __bfloat162float(hp[(size_t)(p.x >> BKSH) * 16 + k]) * __int_as_float(p.y);
        }
    }
    // reduce across the 4 edge groups
    acc += __shfl_xor(acc, 16, 64);
    acc += __shfl_xor(acc, 32, 64);
    if (g == 0)
        __builtin_nontemporal_store(acc, &z[(size_t)node * DIM + ph * 16 + k]);
}

// ---------- fallback: atomic scatter ----------
__global__ void fa_edge_scatter_atomic(const float* __restrict__ h,
                                       const float* __restrict__ d,
                                       const float* __restrict__ gd,
                                       const float* __restrict__ gs,
                                       const int* __restrict__ esrc,
                                       const int* __restrict__ edst,
                                       const float* __restrict__ gate_b,
                                       float* __restrict__ z, int E) {
    int gid  = blockIdx.x * blockDim.x + threadIdx.x;
    int edge = gid >> 6;
    int lane = threadIdx.x & 63;
    if (edge >= E) return;
    int s = esrc[edge];
    int t = edst[edge];
    float g  = fast_tanh(gd[t] + gs[s] + gate_b[0]);
    float ev = g * d[t] * d[s];
    atomicAdd(&z[(size_t)t * DIM + lane], h[(size_t)s * DIM + lane] * ev);
}

extern "C" void kernel_launch(void* const* d_in, const int* in_sizes, int n_in,
                              void* d_out, int out_size, void* d_ws, size_t ws_size,
                              hipStream_t stream) {
    const float* h      = (const float*)d_in[0];
    const float* d      = (const float*)d_in[1];
    const float* gate_W = (const float*)d_in[2];
    const float* gate_b = (const float*)d_in[3];
    const int*   esrc   = (const int*)d_in[4];
    const int*   edst   = (const int*)d_in[5];
    float*       z      = (float*)d_out;

    int N = in_sizes[1];
    int E = in_sizes[4];
    int nbk = (N + BKN - 1) >> BKSH;

    // workspace layout
    char* w = (char*)d_ws;
    float* gd    = (float*)w;          w += (size_t)N * 4;
    float* gs    = (float*)w;          w += (size_t)N * 4;
    int*   bktot = (int*)w;            w += (size_t)MAXBK * 4;
    int*   bkoff = (int*)w;            w += (size_t)MAXBK * 4;
    int*   flags = (int*)w;            w += (size_t)MAXBK * 4;
    int*   cnt   = (int*)w;            w += (size_t)SORTB * MAXBK * 4;  // 1.64 MB
    int*   off   = (int*)w;            w += (size_t)(N + 1) * 4;
    w = (char*)(((uintptr_t)w + 63) & ~(uintptr_t)63);
    int2* pairs  = (int2*)w;           w += ((size_t)E + 64) * 8;
    __hip_bfloat16* hb = (__hip_bfloat16*)w;
    w += (size_t)N * DIM * 2;
    size_t required = (size_t)(w - (char*)d_ws);
    size_t atomic_required = (size_t)N * 8;

    bool use_sort = (ws_size >= required) && (nbk <= MAXBK);

    fa_node_gates<<<(N + 3) / 4, 256, 0, stream>>>(h, gate_W, gd, gs,
                                                   use_sort ? hb : (__hip_bfloat16*)nullptr, N);

    if (use_sort) {
        hipMemsetAsync(flags, 0, (size_t)MAXBK * 4, stream);
        fa_sort_hist<<<SORTB, SORTT, 0, stream>>>(edst, cnt, E);
        fa_sort_scanA<<<nbk, SORTB, 0, stream>>>(cnt, bktot);
        fa_sort_scanB<<<1, 1024, 0, stream>>>(bktot, bkoff, off, nbk, E, N);
        fa_sort_place<<<SORTB, SORTT, 0, stream>>>(gd, gs, d, esrc, edst, gate_b,
                                                   cnt, bkoff, pairs, E, nbk);
        fa_stage2<<<nbk, 256, 0, stream>>>(pairs, bkoff, bktot, off, flags, N);
        dim3 gg((N * 64 + 255) / 256, NPH);
        fa_gather4<<<gg, 256, 0, stream>>>(hb, off, bkoff, bktot, flags, pairs, z, N);
    } else if (ws_size >= atomic_required) {
        hipMemsetAsync(z, 0, (size_t)out_size * sizeof(float), stream);
        fa_edge_scatter_atomic<<<(E + 3) / 4, 256, 0, stream>>>(h, d, gd, gs, esrc,
                                                                edst, gate_b, z, E);
    }
}

// Round 8
// 264.151 us; speedup vs baseline: 1.5057x; 1.5057x over previous
//
#include <hip/hip_runtime.h>
#include <hip/hip_bf16.h>

#define DIM 64
#define BKN 128              // nodes per bucket
#define BKSH 7               // log2(BKN)
#define MAXBK 800            // supports N <= 102400
#define SORTB 512            // blocks for the two-pass sort
#define SORTT 512            // threads per sort block
#define CAP 7500             // stage-2 LDS record capacity (60 KB); mean is ~4096

__device__ inline float fast_tanh(float x) {
    float e = __expf(2.0f * x);
    return 1.0f - 2.0f / (e + 1.0f);
}

// ---------- gates: per-node dot products + bf16 copy of h ----------
__global__ void fa_node_gates(const float* __restrict__ h,
                              const float* __restrict__ gate_W,
                              float* __restrict__ gd,
                              float* __restrict__ gs,
                              __hip_bfloat16* __restrict__ hb,   // may be null
                              int N) {
    int gid  = blockIdx.x * blockDim.x + threadIdx.x;
    int node = gid >> 6;
    int lane = threadIdx.x & 63;
    if (node >= N) return;
    float x = h[(size_t)node * DIM + lane];
    if (hb) hb[(size_t)node * DIM + lane] = __float2bfloat16(x);
    float a = x * gate_W[lane];
    float b = x * gate_W[DIM + lane];
    #pragma unroll
    for (int off = 32; off >= 1; off >>= 1) {
        a += __shfl_xor(a, off, 64);
        b += __shfl_xor(b, off, 64);
    }
    if (lane == 0) {
        gd[node] = a;
        gs[node] = b;
    }
}

// ---------- pass 1: per-block bucket histogram (cnt[blk*MAXBK + bk]) ----------
__global__ void fa_sort_hist(const int* __restrict__ edst, int* __restrict__ cnt, int E) {
    __shared__ int lh[MAXBK];
    int tid = threadIdx.x;
    for (int i = tid; i < MAXBK; i += blockDim.x) lh[i] = 0;
    __syncthreads();
    int chunk = (E + gridDim.x - 1) / gridDim.x;
    int c0 = blockIdx.x * chunk;
    int c1 = min(E, c0 + chunk);
    for (int i = c0 + tid; i < c1; i += blockDim.x)
        atomicAdd(&lh[edst[i] >> BKSH], 1);
    __syncthreads();
    for (int i = tid; i < MAXBK; i += blockDim.x)
        cnt[blockIdx.x * MAXBK + i] = lh[i];
}

// ---------- scan A: per-bucket exclusive prefix over blocks; bucket totals ----------
__global__ void fa_sort_scanA(int* __restrict__ cnt, int* __restrict__ bktot) {
    __shared__ int sc[SORTB];
    int bk  = blockIdx.x;
    int tid = threadIdx.x;
    int v = cnt[tid * MAXBK + bk];
    sc[tid] = v;
    __syncthreads();
    for (int dd = 1; dd < SORTB; dd <<= 1) {
        int t = (tid >= dd) ? sc[tid - dd] : 0;
        __syncthreads();
        sc[tid] += t;
        __syncthreads();
    }
    cnt[tid * MAXBK + bk] = sc[tid] - v;
    if (tid == SORTB - 1) bktot[bk] = sc[tid];
}

// ---------- scan B: exclusive scan of bucket totals; off[N] = E sentinel ----------
__global__ void fa_sort_scanB(const int* __restrict__ bktot, int* __restrict__ bkoff,
                              int* __restrict__ off, int nbk, int E, int N) {
    __shared__ int sc[1024];
    int tid = threadIdx.x;
    int v = (tid < nbk) ? bktot[tid] : 0;
    sc[tid] = v;
    __syncthreads();
    for (int dd = 1; dd < 1024; dd <<= 1) {
        int t = (tid >= dd) ? sc[tid - dd] : 0;
        __syncthreads();
        sc[tid] += t;
        __syncthreads();
    }
    if (tid < nbk) bkoff[tid] = sc[tid] - v;
    if (tid == 0) off[N] = E;
}

// ---------- pass 2: gate compute + place record in bucket region ----------
__global__ void fa_sort_place(const float* __restrict__ gd, const float* __restrict__ gs,
                              const float* __restrict__ d,
                              const int* __restrict__ esrc, const int* __restrict__ edst,
                              const float* __restrict__ gate_b,
                              const int* __restrict__ cnt, const int* __restrict__ bkoff,
                              int2* __restrict__ pairs, int E, int nbk) {
    __shared__ int lcur[MAXBK];
    int tid = threadIdx.x;
    for (int i = tid; i < nbk; i += blockDim.x)
        lcur[i] = bkoff[i] + cnt[blockIdx.x * MAXBK + i];
    __syncthreads();
    int chunk = (E + gridDim.x - 1) / gridDim.x;
    int c0 = blockIdx.x * chunk;
    int c1 = min(E, c0 + chunk);
    float gb = gate_b[0];
    for (int i = c0 + tid; i < c1; i += blockDim.x) {
        int t = edst[i];
        int s = esrc[i];
        float g  = fast_tanh(gd[t] + gs[s] + gb);
        float ev = g * d[t] * d[s];
        int bk = t >> BKSH;
        int pos = atomicAdd(&lcur[bk], 1);       // LDS atomic
        pairs[pos] = make_int2((s << BKSH) | (t & (BKN - 1)), __float_as_int(ev));
    }
}

// ---------- stage 2: in-LDS per-node counting sort within each bucket ----------
__global__ void fa_stage2(int2* __restrict__ pairs,
                          const int* __restrict__ bkoff, const int* __restrict__ bktot,
                          int* __restrict__ off, int* __restrict__ flags, int N) {
    __shared__ int2 buf[CAP];                    // 60 KB
    __shared__ int hist[BKN];
    __shared__ int sc[BKN];
    __shared__ int cur[BKN];
    int bk  = blockIdx.x;
    int tid = threadIdx.x;                       // 256 threads
    int s0  = bkoff[bk];
    int c   = bktot[bk];
    if (c > CAP) {                               // adversarial skew: leave unsorted
        if (tid == 0) {
            flags[bk] = 1;
            int n0 = bk << BKSH;
            if (n0 < N) off[n0] = s0;
        }
        return;
    }
    if (tid < BKN) hist[tid] = 0;
    __syncthreads();
    for (int i = tid; i < c; i += blockDim.x) {
        int2 r = pairs[s0 + i];
        buf[i] = r;
        atomicAdd(&hist[r.x & (BKN - 1)], 1);
    }
    __syncthreads();
    int v = (tid < BKN) ? hist[tid] : 0;
    if (tid < BKN) sc[tid] = v;
    __syncthreads();
    for (int dd = 1; dd < BKN; dd <<= 1) {
        int t = (tid < BKN && tid >= dd) ? sc[tid - dd] : 0;
        __syncthreads();
        if (tid < BKN) sc[tid] += t;
        __syncthreads();
    }
    if (tid < BKN) {
        int excl = sc[tid] - v;
        cur[tid] = excl;
        int node = (bk << BKSH) + tid;
        if (node < N) off[node] = s0 + excl;
    }
    __syncthreads();
    for (int i = tid; i < c; i += blockDim.x) {
        int2 r = buf[i];
        int p = atomicAdd(&cur[r.x & (BKN - 1)], 1);   // LDS atomic
        pairs[s0 + p] = r;
    }
}

// ---------- gather: wave per node, 8-deep MLP, nt pairs stream ----------
__global__ void fa_gather3(const __hip_bfloat16* __restrict__ hb,
                           const int* __restrict__ off,
                           const int* __restrict__ bkoff, const int* __restrict__ bktot,
                           const int* __restrict__ flags,
                           const int2* __restrict__ pairs,
                           float* __restrict__ z, int N) {
    int gid  = blockIdx.x * blockDim.x + threadIdx.x;
    int node = gid >> 6;
    int lane = threadIdx.x & 63;
    if (node >= N) return;
    int bk = node >> BKSH;
    float a0 = 0.f, a1 = 0.f, a2 = 0.f, a3 = 0.f;
    if (!flags[bk]) {
        int j   = off[node];
        int end = off[node + 1];
        // 8-deep unrolled: 8 independent hb-row loads in flight
        for (; j + 8 <= end; j += 8) {
            long long r0 = __builtin_nontemporal_load((const long long*)(pairs + j));
            long long r1 = __builtin_nontemporal_load((const long long*)(pairs + j + 1));
            long long r2 = __builtin_nontemporal_load((const long long*)(pairs + j + 2));
            long long r3 = __builtin_nontemporal_load((const long long*)(pairs + j + 3));
            long long r4 = __builtin_nontemporal_load((const long long*)(pairs + j + 4));
            long long r5 = __builtin_nontemporal_load((const long long*)(pairs + j + 5));
            long long r6 = __builtin_nontemporal_load((const long long*)(pairs + j + 6));
            long long r7 = __builtin_nontemporal_load((const long long*)(pairs + j + 7));
            float h0 = __bfloat162float(hb[((size_t)(((int)r0) >> BKSH)) * DIM + lane]);
            float h1 = __bfloat162float(hb[((size_t)(((int)r1) >> BKSH)) * DIM + lane]);
            float h2 = __bfloat162float(hb[((size_t)(((int)r2) >> BKSH)) * DIM + lane]);
            float h3 = __bfloat162float(hb[((size_t)(((int)r3) >> BKSH)) * DIM + lane]);
            float h4 = __bfloat162float(hb[((size_t)(((int)r4) >> BKSH)) * DIM + lane]);
            float h5 = __bfloat162float(hb[((size_t)(((int)r5) >> BKSH)) * DIM + lane]);
            float h6 = __bfloat162float(hb[((size_t)(((int)r6) >> BKSH)) * DIM + lane]);
            float h7 = __bfloat162float(hb[((size_t)(((int)r7) >> BKSH)) * DIM + lane]);
            a0 += h0 * __int_as_float((int)(r0 >> 32));
            a1 += h1 * __int_as_float((int)(r1 >> 32));
            a2 += h2 * __int_as_float((int)(r2 >> 32));
            a3 += h3 * __int_as_float((int)(r3 >> 32));
            a0 += h4 * __int_as_float((int)(r4 >> 32));
            a1 += h5 * __int_as_float((int)(r5 >> 32));
            a2 += h6 * __int_as_float((int)(r6 >> 32));
            a3 += h7 * __int_as_float((int)(r7 >> 32));
        }
        for (; j < end; ++j) {
            long long r = __builtin_nontemporal_load((const long long*)(pairs + j));
            a0 += __bfloat162float(hb[((size_t)(((int)r) >> BKSH)) * DIM + lane])
                  * __int_as_float((int)(r >> 32));
        }
    } else {
        // correct slow path for oversized (unsorted) buckets
        int s0 = bkoff[bk], end = s0 + bktot[bk];
        int want = node & (BKN - 1);
        for (int j = s0; j < end; ++j) {
            int2 p = pairs[j];
            if ((p.x & (BKN - 1)) == want)
                a0 += __bfloat162float(hb[((size_t)(p.x >> BKSH)) * DIM + lane])
                      * __int_as_float(p.y);
        }
    }
    __builtin_nontemporal_store(a0 + a1 + a2 + a3, &z[(size_t)node * DIM + lane]);
}

// ---------- fallback: atomic scatter ----------
__global__ void fa_edge_scatter_atomic(const float* __restrict__ h,
                                       const float* __restrict__ d,
                                       const float* __restrict__ gd,
                                       const float* __restrict__ gs,
                                       const int* __restrict__ esrc,
                                       const int* __restrict__ edst,
                                       const float* __restrict__ gate_b,
                                       float* __restrict__ z, int E) {
    int gid  = blockIdx.x * blockDim.x + threadIdx.x;
    int edge = gid >> 6;
    int lane = threadIdx.x & 63;
    if (edge >= E) return;
    int s = esrc[edge];
    int t = edst[edge];
    float g  = fast_tanh(gd[t] + gs[s] + gate_b[0]);
    float ev = g * d[t] * d[s];
    atomicAdd(&z[(size_t)t * DIM + lane], h[(size_t)s * DIM + lane] * ev);
}

extern "C" void kernel_launch(void* const* d_in, const int* in_sizes, int n_in,
                              void* d_out, int out_size, void* d_ws, size_t ws_size,
                              hipStream_t stream) {
    const float* h      = (const float*)d_in[0];
    const float* d      = (const float*)d_in[1];
    const float* gate_W = (const float*)d_in[2];
    const float* gate_b = (const float*)d_in[3];
    const int*   esrc   = (const int*)d_in[4];
    const int*   edst   = (const int*)d_in[5];
    float*       z      = (float*)d_out;

    int N = in_sizes[1];
    int E = in_sizes[4];
    int nbk = (N + BKN - 1) >> BKSH;

    // workspace layout
    char* w = (char*)d_ws;
    float* gd    = (float*)w;          w += (size_t)N * 4;
    float* gs    = (float*)w;          w += (size_t)N * 4;
    int*   bktot = (int*)w;            w += (size_t)MAXBK * 4;
    int*   bkoff = (int*)w;            w += (size_t)MAXBK * 4;
    int*   flags = (int*)w;            w += (size_t)MAXBK * 4;
    int*   cnt   = (int*)w;            w += (size_t)SORTB * MAXBK * 4;  // 1.64 MB
    int*   off   = (int*)w;            w += (size_t)(N + 1) * 4;
    w = (char*)(((uintptr_t)w + 63) & ~(uintptr_t)63);
    int2* pairs  = (int2*)w;           w += ((size_t)E + 64) * 8;
    __hip_bfloat16* hb = (__hip_bfloat16*)w;
    w += (size_t)N * DIM * 2;
    size_t required = (size_t)(w - (char*)d_ws);
    size_t atomic_required = (size_t)N * 8;

    bool use_sort = (ws_size >= required) && (nbk <= MAXBK);

    fa_node_gates<<<(N + 3) / 4, 256, 0, stream>>>(h, gate_W, gd, gs,
                                                   use_sort ? hb : (__hip_bfloat16*)nullptr, N);

    if (use_sort) {
        hipMemsetAsync(flags, 0, (size_t)MAXBK * 4, stream);
        fa_sort_hist<<<SORTB, SORTT, 0, stream>>>(edst, cnt, E);
        fa_sort_scanA<<<nbk, SORTB, 0, stream>>>(cnt, bktot);
        fa_sort_scanB<<<1, 1024, 0, stream>>>(bktot, bkoff, off, nbk, E, N);
        fa_sort_place<<<SORTB, SORTT, 0, stream>>>(gd, gs, d, esrc, edst, gate_b,
                                                   cnt, bkoff, pairs, E, nbk);
        fa_stage2<<<nbk, 256, 0, stream>>>(pairs, bkoff, bktot, off, flags, N);
        fa_gather3<<<(N * 64 + 255) / 256, 256, 0, stream>>>(hb, off, bkoff, bktot,
                                                             flags, pairs, z, N);
    } else if (ws_size >= atomic_required) {
        hipMemsetAsync(z, 0, (size_t)out_size * sizeof(float), stream);
        fa_edge_scatter_atomic<<<(E + 3) / 4, 256, 0, stream>>>(h, d, gd, gs, esrc,
                                                                edst, gate_b, z, E);
    }
}

// Round 9
// 195.829 us; speedup vs baseline: 2.0311x; 1.3489x over previous
//
#include <hip/hip_runtime.h>
#include <hip/hip_bf16.h>

#define DIM 64
#define BKN 32               // nodes per bucket
#define BKSH 5               // log2(BKN)
#define MAXBK 3200           // supports N <= 102400
#define SORTB 256            // blocks for the two-pass sort
#define SORTT 512            // threads per sort block
#define CAP 2048             // fused-gather LDS record capacity (16 KB); mean ~1024

__device__ inline float fast_tanh(float x) {
    float e = __expf(2.0f * x);
    return 1.0f - 2.0f / (e + 1.0f);
}

// ---------- gates: per-node dot products + bf16 copy of h ----------
__global__ void fa_node_gates(const float* __restrict__ h,
                              const float* __restrict__ gate_W,
                              float* __restrict__ gd,
                              float* __restrict__ gs,
                              __hip_bfloat16* __restrict__ hb,   // may be null
                              int N) {
    int gid  = blockIdx.x * blockDim.x + threadIdx.x;
    int node = gid >> 6;
    int lane = threadIdx.x & 63;
    if (node >= N) return;
    float x = h[(size_t)node * DIM + lane];
    if (hb) hb[(size_t)node * DIM + lane] = __float2bfloat16(x);
    float a = x * gate_W[lane];
    float b = x * gate_W[DIM + lane];
    #pragma unroll
    for (int off = 32; off >= 1; off >>= 1) {
        a += __shfl_xor(a, off, 64);
        b += __shfl_xor(b, off, 64);
    }
    if (lane == 0) {
        gd[node] = a;
        gs[node] = b;
    }
}

// ---------- pass 1: per-block bucket histogram (cnt[blk*MAXBK + bk]) ----------
__global__ void fa_sort_hist(const int* __restrict__ edst, int* __restrict__ cnt, int E) {
    __shared__ int lh[MAXBK];
    int tid = threadIdx.x;
    for (int i = tid; i < MAXBK; i += blockDim.x) lh[i] = 0;
    __syncthreads();
    int chunk = (E + gridDim.x - 1) / gridDim.x;
    int c0 = blockIdx.x * chunk;
    int c1 = min(E, c0 + chunk);
    for (int i = c0 + tid; i < c1; i += blockDim.x)
        atomicAdd(&lh[edst[i] >> BKSH], 1);
    __syncthreads();
    for (int i = tid; i < MAXBK; i += blockDim.x)
        cnt[blockIdx.x * MAXBK + i] = lh[i];
}

// ---------- scan A: per-bucket exclusive prefix over blocks; bucket totals ----------
// one block per bucket; SORTB threads
__global__ void fa_sort_scanA(int* __restrict__ cnt, int* __restrict__ bktot) {
    __shared__ int sc[SORTB];
    int bk  = blockIdx.x;
    int tid = threadIdx.x;
    int v = cnt[tid * MAXBK + bk];
    sc[tid] = v;
    __syncthreads();
    for (int dd = 1; dd < SORTB; dd <<= 1) {
        int t = (tid >= dd) ? sc[tid - dd] : 0;
        __syncthreads();
        sc[tid] += t;
        __syncthreads();
    }
    cnt[tid * MAXBK + bk] = sc[tid] - v;
    if (tid == SORTB - 1) bktot[bk] = sc[tid];
}

// ---------- scan B: exclusive scan of bucket totals (4 items/thread) ----------
__global__ void fa_sort_scanB(const int* __restrict__ bktot, int* __restrict__ bkoff, int nbk) {
    __shared__ int sc[1024];
    int tid = threadIdx.x;
    int base = tid * 4;
    int v[4];
    int s = 0;
    #pragma unroll
    for (int k = 0; k < 4; ++k) {
        int idx = base + k;
        v[k] = (idx < nbk) ? bktot[idx] : 0;
        s += v[k];
    }
    sc[tid] = s;
    __syncthreads();
    for (int dd = 1; dd < 1024; dd <<= 1) {
        int t = (tid >= dd) ? sc[tid - dd] : 0;
        __syncthreads();
        sc[tid] += t;
        __syncthreads();
    }
    int run = sc[tid] - s;
    #pragma unroll
    for (int k = 0; k < 4; ++k) {
        int idx = base + k;
        if (idx < nbk) bkoff[idx] = run;
        run += v[k];
    }
}

// ---------- pass 2: gate compute + place record in bucket region ----------
__global__ void fa_sort_place(const float* __restrict__ gd, const float* __restrict__ gs,
                              const float* __restrict__ d,
                              const int* __restrict__ esrc, const int* __restrict__ edst,
                              const float* __restrict__ gate_b,
                              const int* __restrict__ cnt, const int* __restrict__ bkoff,
                              int2* __restrict__ pairs, int E, int nbk) {
    __shared__ int lcur[MAXBK];
    int tid = threadIdx.x;
    for (int i = tid; i < nbk; i += blockDim.x)
        lcur[i] = bkoff[i] + cnt[blockIdx.x * MAXBK + i];
    __syncthreads();
    int chunk = (E + gridDim.x - 1) / gridDim.x;
    int c0 = blockIdx.x * chunk;
    int c1 = min(E, c0 + chunk);
    float gb = gate_b[0];
    for (int i = c0 + tid; i < c1; i += blockDim.x) {
        int t = edst[i];
        int s = esrc[i];
        float g  = fast_tanh(gd[t] + gs[s] + gb);
        float ev = g * d[t] * d[s];
        int bk = t >> BKSH;
        int pos = atomicAdd(&lcur[bk], 1);       // LDS atomic
        pairs[pos] = make_int2((s << BKSH) | (t & (BKN - 1)), __float_as_int(ev));
    }
}

// ---------- fused: in-LDS per-node counting sort + wave-per-node gather ----------
__global__ __launch_bounds__(256, 8)
void fa_gather_fused(const __hip_bfloat16* __restrict__ hb,
                     const int* __restrict__ bkoff, const int* __restrict__ bktot,
                     const int2* __restrict__ pairs,
                     float* __restrict__ z, int N) {
    __shared__ int2 buf[CAP];                    // 16 KB
    __shared__ int hist[BKN];
    __shared__ int cur[BKN];
    __shared__ int offl[BKN + 1];
    int bk  = blockIdx.x;
    int tid = threadIdx.x;                       // 256 threads = 4 waves
    int s0  = bkoff[bk];
    int c   = bktot[bk];
    int n0  = bk << BKSH;
    int wid  = tid >> 6;
    int lane = tid & 63;
    if (c <= CAP) {
        if (tid < BKN) hist[tid] = 0;
        __syncthreads();
        for (int i = tid; i < c; i += 256)
            atomicAdd(&hist[pairs[s0 + i].x & (BKN - 1)], 1);
        __syncthreads();
        int v = (tid < BKN) ? hist[tid] : 0;
        if (tid < BKN) cur[tid] = v;
        __syncthreads();
        #pragma unroll
        for (int dd = 1; dd < BKN; dd <<= 1) {
            int t = (tid < BKN && tid >= dd) ? cur[tid - dd] : 0;
            __syncthreads();
            if (tid < BKN) cur[tid] += t;
            __syncthreads();
        }
        if (tid < BKN) {
            offl[tid + 1] = cur[tid];            // inclusive -> offl[t+1]
            cur[tid] -= v;                       // exclusive -> cursor
            if (tid == 0) offl[0] = 0;
        }
        __syncthreads();
        for (int i = tid; i < c; i += 256) {     // pairs L2-hot (just read)
            int2 r = pairs[s0 + i];
            int p = atomicAdd(&cur[r.x & (BKN - 1)], 1);
            buf[p] = r;
        }
        __syncthreads();
        for (int ln = wid; ln < BKN; ln += 4) {
            int node = n0 + ln;
            if (node >= N) break;
            int j   = offl[ln];
            int end = offl[ln + 1];
            float a0 = 0.f, a1 = 0.f, a2 = 0.f, a3 = 0.f;
            for (; j + 4 <= end; j += 4) {
                int2 p0 = buf[j];
                int2 p1 = buf[j + 1];
                int2 p2 = buf[j + 2];
                int2 p3 = buf[j + 3];
                a0 += __bfloat162float(hb[((size_t)(p0.x >> BKSH)) * DIM + lane]) * __int_as_float(p0.y);
                a1 += __bfloat162float(hb[((size_t)(p1.x >> BKSH)) * DIM + lane]) * __int_as_float(p1.y);
                a2 += __bfloat162float(hb[((size_t)(p2.x >> BKSH)) * DIM + lane]) * __int_as_float(p2.y);
                a3 += __bfloat162float(hb[((size_t)(p3.x >> BKSH)) * DIM + lane]) * __int_as_float(p3.y);
            }
            for (; j < end; ++j) {
                int2 p = buf[j];
                a0 += __bfloat162float(hb[((size_t)(p.x >> BKSH)) * DIM + lane]) * __int_as_float(p.y);
            }
            z[(size_t)node * DIM + lane] = a0 + a1 + a2 + a3;
        }
    } else {
        // adversarial-skew slow path: filter directly from global (correct, rare)
        for (int ln = wid; ln < BKN; ln += 4) {
            int node = n0 + ln;
            if (node >= N) break;
            float a0 = 0.f;
            for (int j = s0; j < s0 + c; ++j) {
                int2 p = pairs[j];
                if ((p.x & (BKN - 1)) == ln)
                    a0 += __bfloat162float(hb[((size_t)(p.x >> BKSH)) * DIM + lane]) * __int_as_float(p.y);
            }
            z[(size_t)node * DIM + lane] = a0;
        }
    }
}

// ---------- fallback: atomic scatter ----------
__global__ void fa_edge_scatter_atomic(const float* __restrict__ h,
                                       const float* __restrict__ d,
                                       const float* __restrict__ gd,
                                       const float* __restrict__ gs,
                                       const int* __restrict__ esrc,
                                       const int* __restrict__ edst,
                                       const float* __restrict__ gate_b,
                                       float* __restrict__ z, int E) {
    int gid  = blockIdx.x * blockDim.x + threadIdx.x;
    int edge = gid >> 6;
    int lane = threadIdx.x & 63;
    if (edge >= E) return;
    int s = esrc[edge];
    int t = edst[edge];
    float g  = fast_tanh(gd[t] + gs[s] + gate_b[0]);
    float ev = g * d[t] * d[s];
    atomicAdd(&z[(size_t)t * DIM + lane], h[(size_t)s * DIM + lane] * ev);
}

extern "C" void kernel_launch(void* const* d_in, const int* in_sizes, int n_in,
                              void* d_out, int out_size, void* d_ws, size_t ws_size,
                              hipStream_t stream) {
    const float* h      = (const float*)d_in[0];
    const float* d      = (const float*)d_in[1];
    const float* gate_W = (const float*)d_in[2];
    const float* gate_b = (const float*)d_in[3];
    const int*   esrc   = (const int*)d_in[4];
    const int*   edst   = (const int*)d_in[5];
    float*       z      = (float*)d_out;

    int N = in_sizes[1];
    int E = in_sizes[4];
    int nbk = (N + BKN - 1) >> BKSH;

    // workspace layout
    char* w = (char*)d_ws;
    float* gd    = (float*)w;          w += (size_t)N * 4;
    float* gs    = (float*)w;          w += (size_t)N * 4;
    int*   bktot = (int*)w;            w += (size_t)MAXBK * 4;
    int*   bkoff = (int*)w;            w += (size_t)MAXBK * 4;
    int*   cnt   = (int*)w;            w += (size_t)SORTB * MAXBK * 4;  // 3.28 MB
    w = (char*)(((uintptr_t)w + 63) & ~(uintptr_t)63);
    int2* pairs  = (int2*)w;           w += ((size_t)E + 64) * 8;
    __hip_bfloat16* hb = (__hip_bfloat16*)w;
    w += (size_t)N * DIM * 2;
    size_t required = (size_t)(w - (char*)d_ws);
    size_t atomic_required = (size_t)N * 8;

    bool use_sort = (ws_size >= required) && (nbk <= MAXBK) && (nbk <= 4096);

    fa_node_gates<<<(N + 3) / 4, 256, 0, stream>>>(h, gate_W, gd, gs,
                                                   use_sort ? hb : (__hip_bfloat16*)nullptr, N);

    if (use_sort) {
        fa_sort_hist<<<SORTB, SORTT, 0, stream>>>(edst, cnt, E);
        fa_sort_scanA<<<nbk, SORTB, 0, stream>>>(cnt, bktot);
        fa_sort_scanB<<<1, 1024, 0, stream>>>(bktot, bkoff, nbk);
        fa_sort_place<<<SORTB, SORTT, 0, stream>>>(gd, gs, d, esrc, edst, gate_b,
                                                   cnt, bkoff, pairs, E, nbk);
        fa_gather_fused<<<nbk, 256, 0, stream>>>(hb, bkoff, bktot, pairs, z, N);
    } else if (ws_size >= atomic_required) {
        hipMemsetAsync(z, 0, (size_t)out_size * sizeof(float), stream);
        fa_edge_scatter_atomic<<<(E + 3) / 4, 256, 0, stream>>>(h, d, gd, gs, esrc,
                                                                edst, gate_b, z, E);
    }
}